// Round 4
// baseline (419.979 us; speedup 1.0000x reference)
//
#include <hip/hip_runtime.h>
#include <hip/hip_bf16.h>

#define NS 200000
#define KF 9
#define CC 64

typedef __bf16 bf16_t;
typedef __bf16 bf16x8 __attribute__((ext_vector_type(8)));
typedef __bf16 bf16x4 __attribute__((ext_vector_type(4)));
typedef float f32x4 __attribute__((ext_vector_type(4)));

// ---------------- prep: fp32 -> bf16 features (NS rows), zero stats[256] ----------------
__global__ void k_prep_x(const float* __restrict__ x, bf16_t* __restrict__ xb,
                         float* __restrict__ stats /*256 floats: stats1|stats2*/) {
  int gid = blockIdx.x * blockDim.x + threadIdx.x;
  if (gid < 256) stats[gid] = 0.f;
  long base = (long)gid * 4;
  if (base >= (long)NS * CC) return;
  const float4 v = *(const float4*)(x + base);
  bf16x4 o;
  o[0] = (bf16_t)v.x; o[1] = (bf16_t)v.y; o[2] = (bf16_t)v.z; o[3] = (bf16_t)v.w;
  *(bf16x4*)(xb + base) = o;
}

// ---------------- prep: pack W [K][C][C] fp32 into MFMA B-fragment order, bf16 ----------------
// flat p = (((k*4 + ntile)*2 + kstep)*64 + lane)*8 + j
// value = W[k][ kstep*32 + 8*(lane>>4) + j ][ ntile*16 + (lane&15) ]
__global__ void k_pack_w(const float* __restrict__ W, bf16_t* __restrict__ Wp) {
  int p = blockIdx.x * blockDim.x + threadIdx.x;
  if (p >= KF * 4096) return;
  int j = p & 7;
  int lane = (p >> 3) & 63;
  int kstep = (p >> 9) & 1;
  int ntile = (p >> 10) & 3;
  int k = p >> 12;
  int col = ntile * 16 + (lane & 15);
  int kk = kstep * 32 + 8 * (lane >> 4) + j;
  Wp[p] = (bf16_t)W[(k * CC + kk) * CC + col];
}

// ---------------- conv: register-direct gather-GEMM, 64 sites x 64 ch per block ----------------
// Wave wid owns output cols 16*wid..16*wid+15 for all 64 rows of the block.
// The gather load IS the MFMA A-fragment: no LDS A-tile, no barriers in k-loop.
template <int OUT_F32>
__global__ __launch_bounds__(256, 3) void k_conv(
    const bf16_t* __restrict__ xb,   // NS x 64 bf16 (gather masked: idx>=NS -> 0)
    const int* __restrict__ nbr,     // NS x 9
    const bf16_t* __restrict__ Wp,   // packed 9*4096 bf16
    void* __restrict__ yv,           // NS x 64 raw conv out
    float* __restrict__ stats)       // [128]: sum | sumsq
{
  __shared__ int nbr_s[64 * KF];     // 576 ints
  __shared__ float lred[128];

  const int tid = threadIdx.x;
  const int lane = tid & 63;
  const int wid = tid >> 6;           // wave id = ntile (cols 16*wid..16*wid+15)
  const int row0 = blockIdx.x * 64;
  const int l15 = lane & 15;
  const int lhi = lane >> 4;

  // stage this block's neighbor indices (576 ints) — FULL coverage:
  // [0,256) + [256,512) + [512,576)
  {
    const int* src = nbr + (long)row0 * KF;
    nbr_s[tid] = src[tid];
    nbr_s[tid + 256] = src[tid + 256];
    if (tid < 64) nbr_s[tid + 512] = src[tid + 512];
  }

  bf16x8 vzero;
#pragma unroll
  for (int j = 0; j < 8; ++j) vzero[j] = (bf16_t)0.f;

  f32x4 acc[4];
#pragma unroll
  for (int m = 0; m < 4; ++m) acc[m] = (f32x4){0.f, 0.f, 0.f, 0.f};

  const bf16x8* wp = (const bf16x8*)Wp;
  const char* xbb = (const char*)xb;

  __syncthreads();  // nbr_s ready

#pragma unroll
  for (int k = 0; k < KF; ++k) {
    // this wave's two B-fragments for offset k (coalesced, L2-resident)
    bf16x8 b0 = wp[((k * 4 + wid) * 2 + 0) * 64 + lane];
    bf16x8 b1 = wp[((k * 4 + wid) * 2 + 1) * 64 + lane];
#pragma unroll
    for (int m = 0; m < 4; ++m) {
      unsigned u = (unsigned)nbr_s[(16 * m + l15) * KF + k];
      unsigned row = (u < NS) ? u : 0u;
      const char* src = xbb + (size_t)row * 128u;
      bf16x8 a0 = *(const bf16x8*)(src + lhi * 16);        // ch 8*lhi..8*lhi+7
      bf16x8 a1 = *(const bf16x8*)(src + 64 + lhi * 16);   // ch 32+8*lhi..+7
      if (u >= NS) { a0 = vzero; a1 = vzero; }
      acc[m] = __builtin_amdgcn_mfma_f32_16x16x32_bf16(a0, b0, acc[m], 0, 0, 0);
      acc[m] = __builtin_amdgcn_mfma_f32_16x16x32_bf16(a1, b1, acc[m], 0, 0, 0);
    }
  }

  // epilogue: write y + per-channel partial sums for BN
  // C/D layout (m89): col = lane&15, row = 4*(lane>>4) + reg_idx (within 16x16 tile)
  float csum = 0.f, csq = 0.f;
  const int col = wid * 16 + l15;
  bf16_t* yb = (bf16_t*)yv;
  float* yf = (float*)yv;
#pragma unroll
  for (int m = 0; m < 4; ++m) {
    const int rb = row0 + 16 * m + 4 * lhi;
#pragma unroll
    for (int j = 0; j < 4; ++j) {
      float v = acc[m][j];
      csum += v;
      csq += v * v;
      if (OUT_F32) yf[(long)(rb + j) * CC + col] = v;
      else         yb[(long)(rb + j) * CC + col] = (bf16_t)v;
    }
  }
  csum += __shfl_xor(csum, 16); csum += __shfl_xor(csum, 32);
  csq  += __shfl_xor(csq, 16);  csq  += __shfl_xor(csq, 32);
  if (lane < 16) { lred[col] = csum; lred[64 + col] = csq; }
  __syncthreads();
  if (tid < 64) {
    atomicAdd(&stats[tid], lred[tid]);
    atomicAdd(&stats[64 + tid], lred[64 + tid]);
  }
}

// ---------------- finalize BN: scale/shift from stats ----------------
__global__ void k_finalize(const float* __restrict__ stats, const float* __restrict__ gamma,
                           const float* __restrict__ beta, float* __restrict__ ss) {
  int c = threadIdx.x;
  if (c >= 64) return;
  float invN = 1.0f / (float)NS;
  float mean = stats[c] * invN;
  float var = stats[64 + c] * invN - mean * mean;
  var = fmaxf(var, 0.f);
  float rs = 1.0f / sqrtf(var + 1e-5f);
  float sc = gamma[c] * rs;
  ss[c] = sc;
  ss[64 + c] = beta[c] - mean * sc;
}

// ---------------- BN + ReLU pass (bf16 in -> bf16 out, NS rows) ----------------
__global__ void k_bnrelu(const bf16_t* __restrict__ in, const float* __restrict__ ss,
                         bf16_t* __restrict__ out) {
  int i = blockIdx.x * blockDim.x + threadIdx.x;
  long base = (long)i * 8;
  if (base >= (long)NS * CC) return;
  bf16x8 v = *(const bf16x8*)(in + base);
  int c0 = (int)(base & 63);
  bf16x8 o;
#pragma unroll
  for (int j = 0; j < 8; ++j) {
    float f = (float)v[j] * ss[c0 + j] + ss[64 + c0 + j];
    o[j] = (bf16_t)fmaxf(f, 0.f);
  }
  *(bf16x8*)(out + base) = o;
}

// ---------------- final: BN2 + residual, fp32, IN PLACE on d_out ----------------
__global__ void k_final(float* __restrict__ io, const float* __restrict__ ss,
                        const float* __restrict__ x) {
  int i = blockIdx.x * blockDim.x + threadIdx.x;
  long base = (long)i * 4;
  if (base >= (long)NS * CC) return;
  float4 v = *(const float4*)(io + base);
  float4 f = *(const float4*)(x + base);
  int c0 = (int)(base & 63);
  v.x = v.x * ss[c0 + 0] + ss[64 + c0 + 0] + f.x;
  v.y = v.y * ss[c0 + 1] + ss[64 + c0 + 1] + f.y;
  v.z = v.z * ss[c0 + 2] + ss[64 + c0 + 2] + f.z;
  v.w = v.w * ss[c0 + 3] + ss[64 + c0 + 3] + f.w;
  *(float4*)(io + base) = v;
}

extern "C" void kernel_launch(void* const* d_in, const int* in_sizes, int n_in,
                              void* d_out, int out_size, void* d_ws, size_t ws_size,
                              hipStream_t stream) {
  const float* features = (const float*)d_in[0];
  const int* nbr        = (const int*)d_in[1];
  const float* W1       = (const float*)d_in[2];
  const float* gamma1   = (const float*)d_in[3];
  const float* beta1    = (const float*)d_in[4];
  const float* W2       = (const float*)d_in[5];
  const float* gamma2   = (const float*)d_in[6];
  const float* beta2    = (const float*)d_in[7];

  // ---- d_out doubles as scratch before the final in-place pass ----
  // phase 1: [xb bf16 25.6MB | o1 bf16 25.6MB]   (both dead before conv2)
  // phase 2: o2 fp32 fills all 51.2MB, then BN2+residual in place.
  bf16_t* xb  = (bf16_t*)d_out;
  bf16_t* o1  = (bf16_t*)((char*)d_out + (size_t)NS * CC * 2);
  float*  o2f = (float*)d_out;

  // ---- d_ws: y1n (25.6MB) + packed weights + stats/ss ----
  char* ws = (char*)d_ws;
  auto alignup = [](size_t x) { return (x + 255) & ~(size_t)255; };
  size_t off = 0;
  bf16_t* y1n = (bf16_t*)(ws + off); off += alignup((size_t)NS * CC * 2);
  bf16_t* W1p = (bf16_t*)(ws + off); off += alignup((size_t)KF * 4096 * 2);
  bf16_t* W2p = (bf16_t*)(ws + off); off += alignup((size_t)KF * 4096 * 2);
  float* stats = (float*)(ws + off); off += alignup(256 * 4);  // stats1|stats2
  float* ss    = (float*)(ws + off); off += alignup(256 * 4);  // ss1|ss2

  k_prep_x<<<12500, 256, 0, stream>>>(features, xb, stats);
  k_pack_w<<<144, 256, 0, stream>>>(W1, W1p);
  k_pack_w<<<144, 256, 0, stream>>>(W2, W2p);

  k_conv<0><<<NS / 64, 256, 0, stream>>>(xb, nbr, W1p, (void*)o1, stats);
  k_finalize<<<1, 64, 0, stream>>>(stats, gamma1, beta1, ss);
  k_bnrelu<<<6250, 256, 0, stream>>>(o1, ss, y1n);

  k_conv<1><<<NS / 64, 256, 0, stream>>>(y1n, nbr, W2p, (void*)o2f, stats + 128);
  k_finalize<<<1, 64, 0, stream>>>(stats + 128, gamma2, beta2, ss + 128);
  k_final<<<12500, 256, 0, stream>>>(o2f, ss + 128, features);
}

// Round 6
// 377.562 us; speedup vs baseline: 1.1123x; 1.1123x over previous
//
#include <hip/hip_runtime.h>
#include <hip/hip_bf16.h>

#define NS 200000
#define KF 9
#define CC 64

typedef __bf16 bf16_t;
typedef __bf16 bf16x8 __attribute__((ext_vector_type(8)));
typedef __bf16 bf16x4 __attribute__((ext_vector_type(4)));
typedef float f32x4 __attribute__((ext_vector_type(4)));

// ---------------- combined prep: x->bf16, pack W1/W2, zero stats+zrow ----------------
// grid = 12500 (convert) + 144 (W1) + 144 (W2)
__global__ void k_prep(const float* __restrict__ x, const float* __restrict__ W1,
                       const float* __restrict__ W2, bf16_t* __restrict__ xb,
                       bf16_t* __restrict__ W1p, bf16_t* __restrict__ W2p,
                       float* __restrict__ stats /*256*/, float* __restrict__ zrow /*32*/) {
  const int b = blockIdx.x;
  const int tid = threadIdx.x;
  if (b < 12500) {
    if (b == 0) {          // one-time zeroing
      stats[tid] = 0.f;    // 256 floats
      if (tid < 32) zrow[tid] = 0.f;
    }
    long base = ((long)b * 256 + tid) * 4;
    const float4 v = *(const float4*)(x + base);
    bf16x4 o;
    o[0] = (bf16_t)v.x; o[1] = (bf16_t)v.y; o[2] = (bf16_t)v.z; o[3] = (bf16_t)v.w;
    *(bf16x4*)(xb + base) = o;
    return;
  }
  int b2 = b - 12500;
  const float* W = (b2 < 144) ? W1 : W2;
  bf16_t* Wp = (b2 < 144) ? W1p : W2p;
  if (b2 >= 144) b2 -= 144;
  int p = b2 * 256 + tid;           // [0, 36864)
  int j = p & 7;
  int lane = (p >> 3) & 63;
  int kstep = (p >> 9) & 1;
  int ntile = (p >> 10) & 3;
  int k = p >> 12;
  int col = ntile * 16 + (lane & 15);
  int kk = kstep * 32 + 8 * (lane >> 4) + j;
  Wp[p] = (bf16_t)W[(k * CC + kk) * CC + col];
}

// ---------------- conv: register-pipelined gather-GEMM, 64 sites x 64 ch per block ----
// Wave wid owns output cols 16*wid..+15. Explicit cur/next double-buffer of A and B
// fragments; all 8 gathers + 2 weight loads for k+1 issued before k's 8 MFMAs.
template <int OUT_F32>
__global__ __launch_bounds__(256, 3) void k_conv(
    const bf16_t* __restrict__ xb,   // NS x 64 bf16
    const int* __restrict__ nbr,     // NS x 9  (value NS == "no neighbor")
    const bf16_t* __restrict__ Wp,   // packed 9*4096 bf16
    void* __restrict__ yv,           // NS x 64 raw conv out
    float* __restrict__ stats,       // [128]: sum | sumsq
    const char* __restrict__ zrow)   // 128B of zeros (sentinel gather target)
{
  __shared__ int nbr_s[64 * KF];     // 576 ints
  __shared__ float lred[128];

  const int tid = threadIdx.x;
  const int lane = tid & 63;
  const int wid = tid >> 6;
  const int row0 = blockIdx.x * 64;
  const int l15 = lane & 15;
  const int lhi = lane >> 4;

  {
    const int* src = nbr + (long)row0 * KF;
    nbr_s[tid] = src[tid];
    nbr_s[tid + 256] = src[tid + 256];
    if (tid < 64) nbr_s[tid + 512] = src[tid + 512];
  }
  __syncthreads();

  // all 36 per-lane row indices -> VGPRs (statically indexed after unroll)
  int idx[4][KF];
#pragma unroll
  for (int m = 0; m < 4; ++m)
#pragma unroll
    for (int k = 0; k < KF; ++k)
      idx[m][k] = nbr_s[(16 * m + l15) * KF + k];

  const char* xbb = (const char*)xb;
  auto arow = [&](int m, int k) -> const char* {
    unsigned u = (unsigned)idx[m][k];
    return (u < NS) ? (xbb + (size_t)u * 128u) : zrow;  // pointer-select, no data fixup
  };

  const bf16x8* wp = (const bf16x8*)Wp;

  f32x4 acc[4];
#pragma unroll
  for (int m = 0; m < 4; ++m) acc[m] = (f32x4){0.f, 0.f, 0.f, 0.f};

  bf16x8 cA0[4], cA1[4], nA0[4], nA1[4];
  bf16x8 b0, b1, nb0, nb1;

  // prologue: k = 0 fragments
#pragma unroll
  for (int m = 0; m < 4; ++m) {
    const char* s = arow(m, 0);
    cA0[m] = *(const bf16x8*)(s + lhi * 16);
    cA1[m] = *(const bf16x8*)(s + 64 + lhi * 16);
  }
  b0 = wp[((0 * 4 + wid) * 2 + 0) * 64 + lane];
  b1 = wp[((0 * 4 + wid) * 2 + 1) * 64 + lane];

#pragma unroll
  for (int k = 0; k < KF; ++k) {
    if (k + 1 < KF) {   // issue next-k loads BEFORE this k's MFMAs
#pragma unroll
      for (int m = 0; m < 4; ++m) {
        const char* s = arow(m, k + 1);
        nA0[m] = *(const bf16x8*)(s + lhi * 16);
        nA1[m] = *(const bf16x8*)(s + 64 + lhi * 16);
      }
      nb0 = wp[(((k + 1) * 4 + wid) * 2 + 0) * 64 + lane];
      nb1 = wp[(((k + 1) * 4 + wid) * 2 + 1) * 64 + lane];
    }
    __builtin_amdgcn_s_setprio(1);
#pragma unroll
    for (int m = 0; m < 4; ++m)
      acc[m] = __builtin_amdgcn_mfma_f32_16x16x32_bf16(cA0[m], b0, acc[m], 0, 0, 0);
#pragma unroll
    for (int m = 0; m < 4; ++m)
      acc[m] = __builtin_amdgcn_mfma_f32_16x16x32_bf16(cA1[m], b1, acc[m], 0, 0, 0);
    __builtin_amdgcn_s_setprio(0);
#pragma unroll
    for (int m = 0; m < 4; ++m) { cA0[m] = nA0[m]; cA1[m] = nA1[m]; }
    b0 = nb0; b1 = nb1;
  }

  // epilogue: write y + per-channel partial sums for BN
  // C/D layout (m89): col = lane&15, row = 4*(lane>>4) + reg_idx (within 16x16 tile)
  float csum = 0.f, csq = 0.f;
  const int col = wid * 16 + l15;
  bf16_t* yb = (bf16_t*)yv;
  float* yf = (float*)yv;
#pragma unroll
  for (int m = 0; m < 4; ++m) {
    const int rb = row0 + 16 * m + 4 * lhi;
#pragma unroll
    for (int j = 0; j < 4; ++j) {
      float v = acc[m][j];
      csum += v;
      csq += v * v;
      if (OUT_F32) yf[(long)(rb + j) * CC + col] = v;
      else         yb[(long)(rb + j) * CC + col] = (bf16_t)v;
    }
  }
  csum += __shfl_xor(csum, 16); csum += __shfl_xor(csum, 32);
  csq  += __shfl_xor(csq, 16);  csq  += __shfl_xor(csq, 32);
  if (lane < 16) { lred[col] = csum; lred[64 + col] = csq; }
  __syncthreads();
  if (tid < 64) {
    atomicAdd(&stats[tid], lred[tid]);
    atomicAdd(&stats[64 + tid], lred[64 + tid]);
  }
}

// ---------------- BN(+ReLU) finalize folded in: each block recomputes scale/shift ----
__global__ void k_bnrelu(const bf16_t* __restrict__ in, const float* __restrict__ stats,
                         const float* __restrict__ gamma, const float* __restrict__ beta,
                         bf16_t* __restrict__ out) {
  __shared__ float ss_s[128];
  const int tid = threadIdx.x;
  if (tid < 64) {
    const float invN = 1.0f / (float)NS;
    float mean = stats[tid] * invN;
    float var = fmaxf(stats[64 + tid] * invN - mean * mean, 0.f);
    float rs = rsqrtf(var + 1e-5f);
    float sc = gamma[tid] * rs;
    ss_s[tid] = sc;
    ss_s[64 + tid] = beta[tid] - mean * sc;
  }
  __syncthreads();
  long base = ((long)blockIdx.x * 256 + tid) * 8;
  bf16x8 v = *(const bf16x8*)(in + base);
  int c0 = (int)(base & 63);
  bf16x8 o;
#pragma unroll
  for (int j = 0; j < 8; ++j) {
    float f = (float)v[j] * ss_s[c0 + j] + ss_s[64 + c0 + j];
    o[j] = (bf16_t)fmaxf(f, 0.f);
  }
  *(bf16x8*)(out + base) = o;
}

// ---------------- final: BN2 + residual, fp32, IN PLACE on d_out ----------------
__global__ void k_final(float* __restrict__ io, const float* __restrict__ stats,
                        const float* __restrict__ gamma, const float* __restrict__ beta,
                        const float* __restrict__ x) {
  __shared__ float ss_s[128];
  const int tid = threadIdx.x;
  if (tid < 64) {
    const float invN = 1.0f / (float)NS;
    float mean = stats[tid] * invN;
    float var = fmaxf(stats[64 + tid] * invN - mean * mean, 0.f);
    float rs = rsqrtf(var + 1e-5f);
    float sc = gamma[tid] * rs;
    ss_s[tid] = sc;
    ss_s[64 + tid] = beta[tid] - mean * sc;
  }
  __syncthreads();
  long base = ((long)blockIdx.x * 256 + tid) * 4;
  float4 v = *(const float4*)(io + base);
  float4 f = *(const float4*)(x + base);
  int c0 = (int)(base & 63);
  v.x = v.x * ss_s[c0 + 0] + ss_s[64 + c0 + 0] + f.x;
  v.y = v.y * ss_s[c0 + 1] + ss_s[64 + c0 + 1] + f.y;
  v.z = v.z * ss_s[c0 + 2] + ss_s[64 + c0 + 2] + f.z;
  v.w = v.w * ss_s[c0 + 3] + ss_s[64 + c0 + 3] + f.w;
  *(float4*)(io + base) = v;
}

extern "C" void kernel_launch(void* const* d_in, const int* in_sizes, int n_in,
                              void* d_out, int out_size, void* d_ws, size_t ws_size,
                              hipStream_t stream) {
  const float* features = (const float*)d_in[0];
  const int* nbr        = (const int*)d_in[1];
  const float* W1       = (const float*)d_in[2];
  const float* gamma1   = (const float*)d_in[3];
  const float* beta1    = (const float*)d_in[4];
  const float* W2       = (const float*)d_in[5];
  const float* gamma2   = (const float*)d_in[6];
  const float* beta2    = (const float*)d_in[7];

  // d_out doubles as scratch: phase 1 [xb bf16 | o1 bf16], phase 2 fp32 o2 in place.
  bf16_t* xb  = (bf16_t*)d_out;
  bf16_t* o1  = (bf16_t*)((char*)d_out + (size_t)NS * CC * 2);
  float*  o2f = (float*)d_out;

  // d_ws: y1n (25.6MB) + packed weights + stats + zero row
  char* ws = (char*)d_ws;
  auto alignup = [](size_t x) { return (x + 255) & ~(size_t)255; };
  size_t off = 0;
  bf16_t* y1n = (bf16_t*)(ws + off); off += alignup((size_t)NS * CC * 2);
  bf16_t* W1p = (bf16_t*)(ws + off); off += alignup((size_t)KF * 4096 * 2);
  bf16_t* W2p = (bf16_t*)(ws + off); off += alignup((size_t)KF * 4096 * 2);
  float* stats = (float*)(ws + off); off += alignup(256 * 4);  // stats1|stats2
  float* zrow  = (float*)(ws + off); off += alignup(32 * 4);   // 128B zeros

  k_prep<<<12500 + 288, 256, 0, stream>>>(features, W1, W2, xb, W1p, W2p, stats, zrow);

  k_conv<0><<<NS / 64, 256, 0, stream>>>(xb, nbr, W1p, (void*)o1, stats, (const char*)zrow);
  k_bnrelu<<<6250, 256, 0, stream>>>(o1, stats, gamma1, beta1, y1n);

  k_conv<1><<<NS / 64, 256, 0, stream>>>(y1n, nbr, W2p, (void*)o2f, stats + 128, (const char*)zrow);
  k_final<<<12500, 256, 0, stream>>>(o2f, stats + 128, gamma2, beta2, features);
}

// Round 7
// 262.093 us; speedup vs baseline: 1.6024x; 1.4406x over previous
//
#include <hip/hip_runtime.h>
#include <hip/hip_bf16.h>

#define NS 200000
#define KF 9
#define CC 64
#define RPB 128                       // rows per block (4 waves x 32 rows)
#define NB ((NS + RPB - 1) / RPB)     // 1563 (last block: 64 valid rows)

typedef __bf16 bf16_t;
typedef __bf16 bf16x8 __attribute__((ext_vector_type(8)));
typedef __bf16 bf16x4 __attribute__((ext_vector_type(4)));
typedef float f32x4 __attribute__((ext_vector_type(4)));

// ---------------- combined prep: x->bf16, pack W1/W2, zero stats+zrow ----------------
__global__ void k_prep(const float* __restrict__ x, const float* __restrict__ W1,
                       const float* __restrict__ W2, bf16_t* __restrict__ xb,
                       bf16_t* __restrict__ W1p, bf16_t* __restrict__ W2p,
                       float* __restrict__ stats /*256*/, float* __restrict__ zrow /*32*/) {
  const int b = blockIdx.x;
  const int tid = threadIdx.x;
  if (b < 12500) {
    if (b == 0) {          // one-time zeroing
      stats[tid] = 0.f;    // 256 floats
      if (tid < 32) zrow[tid] = 0.f;
    }
    long base = ((long)b * 256 + tid) * 4;
    const float4 v = *(const float4*)(x + base);
    bf16x4 o;
    o[0] = (bf16_t)v.x; o[1] = (bf16_t)v.y; o[2] = (bf16_t)v.z; o[3] = (bf16_t)v.w;
    *(bf16x4*)(xb + base) = o;
    return;
  }
  int b2 = b - 12500;
  const float* W = (b2 < 144) ? W1 : W2;
  bf16_t* Wp = (b2 < 144) ? W1p : W2p;
  if (b2 >= 144) b2 -= 144;
  int p = b2 * 256 + tid;           // [0, 36864)
  int j = p & 7;
  int lane = (p >> 3) & 63;
  int kstep = (p >> 9) & 1;
  int ntile = (p >> 10) & 3;
  int k = p >> 12;
  int col = ntile * 16 + (lane & 15);
  int kk = kstep * 32 + 8 * (lane >> 4) + j;
  Wp[p] = (bf16_t)W[(k * CC + kk) * CC + col];
}

// ---------------- conv: per-wave independent 32 rows x 64 cols, no redundant gather ----
// Block = 128 rows, 4 waves; wave wid owns rows [row0+32*wid, +32). Each gathered
// feature row is fetched exactly once per (row,k) -> 4x less L2/L3 fabric traffic
// than the col-split layout. B-fragments (72KB packed W) are L2-hot re-reads.
template <int OUT_F32>
__global__ __launch_bounds__(256, 3) void k_conv(
    const bf16_t* __restrict__ xb,   // NS x 64 bf16
    const int* __restrict__ nbr,     // NS x 9  (value NS == "no neighbor")
    const bf16_t* __restrict__ Wp,   // packed 9*4096 bf16
    void* __restrict__ yv,           // NS x 64 raw conv out
    float* __restrict__ stats,       // [128]: sum | sumsq
    const char* __restrict__ zrow)   // 128B of zeros (sentinel gather target)
{
  __shared__ int nbr_s[RPB * KF];    // 1152 ints
  __shared__ float lred[8 * CC];     // 4 waves x (sum|sq) x 64 cols

  const int tid = threadIdx.x;
  const int lane = tid & 63;
  const int wid = tid >> 6;
  const int row0 = blockIdx.x * RPB;
  const int l15 = lane & 15;
  const int lhi = lane >> 4;

  // stage this block's neighbor indices, bounds-clamped to sentinel NS
  {
    const long nbase = (long)row0 * KF;
    const long ntot = (long)NS * KF;
#pragma unroll
    for (int t = 0; t < 5; ++t) {
      int p = tid + t * 256;
      if (p < RPB * KF) {
        long g = nbase + p;
        nbr_s[p] = (g < ntot) ? nbr[g] : NS;
      }
    }
  }
  __syncthreads();

  const char* xbb = (const char*)xb;
  const bf16x8* wp = (const bf16x8*)Wp;
  const int r_lo = (32 * wid + l15) * KF;        // LDS idx base, m=0 row
  const int r_hi = (32 * wid + 16 + l15) * KF;   // m=1 row

  auto rowptr = [&](int u) -> const char* {
    return ((unsigned)u < NS) ? (xbb + (size_t)(unsigned)u * 128u) : zrow;
  };

  f32x4 acc[2][4];
#pragma unroll
  for (int m = 0; m < 2; ++m)
#pragma unroll
    for (int n = 0; n < 4; ++n) acc[m][n] = (f32x4){0.f, 0.f, 0.f, 0.f};

  bf16x8 cA[2][2], nA[2][2], cB[4][2], nB[4][2];

  // prologue: k=0 fragments; rolling 2-reg idx prefetch
  int i0 = nbr_s[r_lo + 0], i1 = nbr_s[r_hi + 0];
  {
    const char* s0 = rowptr(i0);
    const char* s1 = rowptr(i1);
    cA[0][0] = *(const bf16x8*)(s0 + lhi * 16);
    cA[0][1] = *(const bf16x8*)(s0 + 64 + lhi * 16);
    cA[1][0] = *(const bf16x8*)(s1 + lhi * 16);
    cA[1][1] = *(const bf16x8*)(s1 + 64 + lhi * 16);
  }
#pragma unroll
  for (int n = 0; n < 4; ++n)
#pragma unroll
    for (int kk = 0; kk < 2; ++kk)
      cB[n][kk] = wp[((0 * 4 + n) * 2 + kk) * 64 + lane];
  i0 = nbr_s[r_lo + 1]; i1 = nbr_s[r_hi + 1];

#pragma unroll
  for (int k = 0; k < KF; ++k) {
    if (k + 1 < KF) {   // issue next-k loads BEFORE this k's MFMAs
      const char* s0 = rowptr(i0);
      const char* s1 = rowptr(i1);
      nA[0][0] = *(const bf16x8*)(s0 + lhi * 16);
      nA[0][1] = *(const bf16x8*)(s0 + 64 + lhi * 16);
      nA[1][0] = *(const bf16x8*)(s1 + lhi * 16);
      nA[1][1] = *(const bf16x8*)(s1 + 64 + lhi * 16);
#pragma unroll
      for (int n = 0; n < 4; ++n)
#pragma unroll
        for (int kk = 0; kk < 2; ++kk)
          nB[n][kk] = wp[(((k + 1) * 4 + n) * 2 + kk) * 64 + lane];
      if (k + 2 < KF) { i0 = nbr_s[r_lo + k + 2]; i1 = nbr_s[r_hi + k + 2]; }
    }
    __builtin_amdgcn_s_setprio(1);
#pragma unroll
    for (int m = 0; m < 2; ++m)
#pragma unroll
      for (int n = 0; n < 4; ++n)
        acc[m][n] = __builtin_amdgcn_mfma_f32_16x16x32_bf16(cA[m][0], cB[n][0], acc[m][n], 0, 0, 0);
#pragma unroll
    for (int m = 0; m < 2; ++m)
#pragma unroll
      for (int n = 0; n < 4; ++n)
        acc[m][n] = __builtin_amdgcn_mfma_f32_16x16x32_bf16(cA[m][1], cB[n][1], acc[m][n], 0, 0, 0);
    __builtin_amdgcn_s_setprio(0);
#pragma unroll
    for (int m = 0; m < 2; ++m) { cA[m][0] = nA[m][0]; cA[m][1] = nA[m][1]; }
#pragma unroll
    for (int n = 0; n < 4; ++n) { cB[n][0] = nB[n][0]; cB[n][1] = nB[n][1]; }
  }

  // epilogue: store y (guarded for tail block) + per-channel BN partials
  // C/D layout (m89): col = lane&15, row = 4*(lane>>4) + reg_idx (within 16x16 tile)
  float csum[4] = {0.f, 0.f, 0.f, 0.f}, csq[4] = {0.f, 0.f, 0.f, 0.f};
  bf16_t* yb = (bf16_t*)yv;
  float* yf = (float*)yv;
#pragma unroll
  for (int m = 0; m < 2; ++m) {
    const int rb0 = row0 + 32 * wid + 16 * m + 4 * lhi;
#pragma unroll
    for (int n = 0; n < 4; ++n) {
      const int col = 16 * n + l15;
#pragma unroll
      for (int j = 0; j < 4; ++j) {
        float v = acc[m][n][j];
        csum[n] += v; csq[n] += v * v;       // invalid rows contribute exact 0
        int rb = rb0 + j;
        if (rb < NS) {
          if (OUT_F32) yf[(long)rb * CC + col] = v;
          else         yb[(long)rb * CC + col] = (bf16_t)v;
        }
      }
    }
  }
#pragma unroll
  for (int n = 0; n < 4; ++n) {
    csum[n] += __shfl_xor(csum[n], 16); csum[n] += __shfl_xor(csum[n], 32);
    csq[n]  += __shfl_xor(csq[n], 16);  csq[n]  += __shfl_xor(csq[n], 32);
  }
  if (lane < 16) {
#pragma unroll
    for (int n = 0; n < 4; ++n) {
      lred[wid * CC + 16 * n + l15] = csum[n];
      lred[4 * CC + wid * CC + 16 * n + l15] = csq[n];
    }
  }
  __syncthreads();
  if (tid < CC) {
    float s = lred[tid] + lred[CC + tid] + lred[2 * CC + tid] + lred[3 * CC + tid];
    float q = lred[4 * CC + tid] + lred[5 * CC + tid] + lred[6 * CC + tid] + lred[7 * CC + tid];
    atomicAdd(&stats[tid], s);
    atomicAdd(&stats[64 + tid], q);
  }
}

// ---------------- BN(+ReLU) finalize folded in: each block recomputes scale/shift ----
__global__ void k_bnrelu(const bf16_t* __restrict__ in, const float* __restrict__ stats,
                         const float* __restrict__ gamma, const float* __restrict__ beta,
                         bf16_t* __restrict__ out) {
  __shared__ float ss_s[128];
  const int tid = threadIdx.x;
  if (tid < 64) {
    const float invN = 1.0f / (float)NS;
    float mean = stats[tid] * invN;
    float var = fmaxf(stats[64 + tid] * invN - mean * mean, 0.f);
    float rs = rsqrtf(var + 1e-5f);
    float sc = gamma[tid] * rs;
    ss_s[tid] = sc;
    ss_s[64 + tid] = beta[tid] - mean * sc;
  }
  __syncthreads();
  long base = ((long)blockIdx.x * 256 + tid) * 8;
  bf16x8 v = *(const bf16x8*)(in + base);
  int c0 = (int)(base & 63);
  bf16x8 o;
#pragma unroll
  for (int j = 0; j < 8; ++j) {
    float f = (float)v[j] * ss_s[c0 + j] + ss_s[64 + c0 + j];
    o[j] = (bf16_t)fmaxf(f, 0.f);
  }
  *(bf16x8*)(out + base) = o;
}

// ---------------- final: BN2 + residual, fp32, IN PLACE on d_out ----------------
__global__ void k_final(float* __restrict__ io, const float* __restrict__ stats,
                        const float* __restrict__ gamma, const float* __restrict__ beta,
                        const float* __restrict__ x) {
  __shared__ float ss_s[128];
  const int tid = threadIdx.x;
  if (tid < 64) {
    const float invN = 1.0f / (float)NS;
    float mean = stats[tid] * invN;
    float var = fmaxf(stats[64 + tid] * invN - mean * mean, 0.f);
    float rs = rsqrtf(var + 1e-5f);
    float sc = gamma[tid] * rs;
    ss_s[tid] = sc;
    ss_s[64 + tid] = beta[tid] - mean * sc;
  }
  __syncthreads();
  long base = ((long)blockIdx.x * 256 + tid) * 4;
  float4 v = *(const float4*)(io + base);
  float4 f = *(const float4*)(x + base);
  int c0 = (int)(base & 63);
  v.x = v.x * ss_s[c0 + 0] + ss_s[64 + c0 + 0] + f.x;
  v.y = v.y * ss_s[c0 + 1] + ss_s[64 + c0 + 1] + f.y;
  v.z = v.z * ss_s[c0 + 2] + ss_s[64 + c0 + 2] + f.z;
  v.w = v.w * ss_s[c0 + 3] + ss_s[64 + c0 + 3] + f.w;
  *(float4*)(io + base) = v;
}

extern "C" void kernel_launch(void* const* d_in, const int* in_sizes, int n_in,
                              void* d_out, int out_size, void* d_ws, size_t ws_size,
                              hipStream_t stream) {
  const float* features = (const float*)d_in[0];
  const int* nbr        = (const int*)d_in[1];
  const float* W1       = (const float*)d_in[2];
  const float* gamma1   = (const float*)d_in[3];
  const float* beta1    = (const float*)d_in[4];
  const float* W2       = (const float*)d_in[5];
  const float* gamma2   = (const float*)d_in[6];
  const float* beta2    = (const float*)d_in[7];

  // d_out doubles as scratch: phase 1 [xb bf16 | o1 bf16], phase 2 fp32 o2 in place.
  bf16_t* xb  = (bf16_t*)d_out;
  bf16_t* o1  = (bf16_t*)((char*)d_out + (size_t)NS * CC * 2);
  float*  o2f = (float*)d_out;

  // d_ws: y1n (25.6MB) + packed weights + stats + zero row
  char* ws = (char*)d_ws;
  auto alignup = [](size_t x) { return (x + 255) & ~(size_t)255; };
  size_t off = 0;
  bf16_t* y1n = (bf16_t*)(ws + off); off += alignup((size_t)NS * CC * 2);
  bf16_t* W1p = (bf16_t*)(ws + off); off += alignup((size_t)KF * 4096 * 2);
  bf16_t* W2p = (bf16_t*)(ws + off); off += alignup((size_t)KF * 4096 * 2);
  float* stats = (float*)(ws + off); off += alignup(256 * 4);  // stats1|stats2
  float* zrow  = (float*)(ws + off); off += alignup(32 * 4);   // 128B zeros

  k_prep<<<12500 + 288, 256, 0, stream>>>(features, W1, W2, xb, W1p, W2p, stats, zrow);

  k_conv<0><<<NB, 256, 0, stream>>>(xb, nbr, W1p, (void*)o1, stats, (const char*)zrow);
  k_bnrelu<<<6250, 256, 0, stream>>>(o1, stats, gamma1, beta1, y1n);

  k_conv<1><<<NB, 256, 0, stream>>>(y1n, nbr, W2p, (void*)o2f, stats + 128, (const char*)zrow);
  k_final<<<12500, 256, 0, stream>>>(o2f, stats + 128, gamma2, beta2, features);
}